// Round 1
// baseline (16904.419 us; speedup 1.0000x reference)
//
#include <hip/hip_runtime.h>
#include <stdint.h>

// SPINN thin-stack TreeLSTM, MI355X, round 7: K-SPLIT pair decomposition.
// Pair (g2) = blocks (bid, bid+128); block sl owns K-rows {label[sl*32+32),
// hl own-half, hr own-half} x ALL 640 gate cols (W slice still 200 f32/thr).
// NO h/c ever crosses blocks: per step each block sends only the 2x320
// partner-dim partial gate sums as self-tagged (f32,u32 t+1) u64 words into a
// 4-deep ring (agent-scope, no drains, no separate tags, no spin wave).
// h/c records are intra-block only -> plain L1-cached global + barriers.
// Step: P1 passA(all 8 waves, partner cols) | bar | reduce+send, passB(own
// cols, poll loads issued at q==3) | bar | P3 cell(w0-1, tag-check+finish) ||
// prefetch t+1 (w2-4) | bar.  3 barriers/step, GEMM issue floor 1600cy/step.

#define D     512
#define HD    128
#define LD    64
#define NTHR  512

typedef unsigned long long u64t;

__device__ __forceinline__ float sigf(float x){ return 1.0f/(1.0f+__expf(-x)); }
__device__ __forceinline__ float tanh_(float x){ return 1.0f-2.0f/(__expf(2.0f*x)+1.0f); }
__device__ __forceinline__ u64t gld64x(const u64t* p){
  return __hip_atomic_load(p, __ATOMIC_RELAXED, __HIP_MEMORY_SCOPE_AGENT);
}
__device__ __forceinline__ void gst64x(u64t* p, u64t v){
  __hip_atomic_store(p, v, __ATOMIC_RELAXED, __HIP_MEMORY_SCOPE_AGENT);
}
__device__ __forceinline__ u64t packw(float v, unsigned tg){
  return ((u64t)tg << 32) | (u64t)__float_as_uint(v);
}

// One GEMM pass: this wave's 20 K-rows x (5 cols/lane) x 2 batches.
// xs reads are wave-wide broadcasts (conflict-free). HOOK runs once at q==3.
#define GEMM_PASS(WREG, GPDST, HOOK) do { \
  float a0_[5] = {0.f,0.f,0.f,0.f,0.f}; \
  float a1_[5] = {0.f,0.f,0.f,0.f,0.f}; \
  _Pragma("unroll") \
  for (int q=0;q<5;++q){ \
    if (q==3) { HOOK } \
    const int k_ = kg*20 + q*4; \
    const float4 x0_ = *(const float4*)&xs[cur][0][k_]; \
    const float4 x1_ = *(const float4*)&xs[cur][1][k_]; \
    const float xa0_[4] = {x0_.x,x0_.y,x0_.z,x0_.w}; \
    const float xa1_[4] = {x1_.x,x1_.y,x1_.z,x1_.w}; \
    _Pragma("unroll") \
    for (int jj=0;jj<4;++jj){ \
      _Pragma("unroll") \
      for (int g=0;g<5;++g){ \
        const float wv_ = WREG[q*4+jj][g]; \
        a0_[g] = __builtin_fmaf(wv_, xa0_[jj], a0_[g]); \
        a1_[g] = __builtin_fmaf(wv_, xa1_[jj], a1_[g]); \
      } \
    } \
  } \
  _Pragma("unroll") \
  for (int g=0;g<5;++g){ \
    float2 v2_; v2_.x = a0_[g]; v2_.y = a1_[g]; \
    *(float2*)&GPDST[kg][g*128 + lane*2] = v2_; \
  } \
} while(0)

__global__ __launch_bounds__(NTHR,1) void spinn_kernel(
    const int* __restrict__ trans, const int* __restrict__ labels,
    const float* __restrict__ emb, const float* __restrict__ W,
    const float* __restrict__ bias, const float* __restrict__ leaf,
    float* __restrict__ out, u64t* __restrict__ Xbuf,
    float* __restrict__ hrec_g, float* __restrict__ crec_g)
{
  const int bid = blockIdx.x;
  const int g2 = bid & 127, sl = bid >> 7, ps = sl ^ 1;
  const int gb0 = g2*2;
  const int tid = threadIdx.x;
  const int kg = tid >> 6, lane = tid & 63;

  // intra-block records (plain cached; workgroup-scope via barriers)
  float* hrec = hrec_g + (size_t)bid * (D*2*64);
  float* crec = crec_g + (size_t)bid * (D*2*64);

  __shared__ __align__(16) float xs[2][2][160];   // [buf][b][k]: 32 lab|64 hl|64 hr (own halves)
  __shared__ __align__(16) float gpA[8][640];     // partner-col partials [kg][(g*64+d)*2+b]
  __shared__ __align__(16) float gpB[8][640];     // own-col partials
  __shared__ float bsl[320];
  __shared__ float lshd[HD];
  __shared__ float clb[2][2][64];
  __shared__ uint8_t mS[D][2];
  __shared__ short   liA[D][2];
  __shared__ unsigned short stk_[2][D];

  // --- W slices: 20 K-rows x (5 partner cols + 5 own cols) = 200 f32/thread ---
  float wa[20][5], wb[20][5];
#pragma unroll
  for (int j=0;j<20;++j){
    const int i = kg*20 + j;
    const int R = (i<32) ? (sl*32 + i)
                : (i<96) ? (64 + sl*64 + (i-32))
                :          (192 + sl*64 + (i-96));
    const float* Wr = W + (size_t)R*640;
#pragma unroll
    for (int g=0;g<4;++g){
      wa[j][g] = Wr[g*128 + ps*64 + lane];
      wb[j][g] = Wr[g*128 + sl*64 + lane];
    }
    wa[j][4] = Wr[512 + ps*64 + lane];
    wb[j][4] = Wr[512 + sl*64 + lane];
  }

  if (tid < 320){
    const int gc = (tid < 256) ? ((tid>>6)*128 + sl*64 + (tid&63))
                               : (512 + sl*64 + (tid-256));
    bsl[tid] = bias[gc];
  }
  if (tid < HD) lshd[tid] = leaf[tid];
  if (tid < 2){   // precompute (mask, li); ri == t-1 always on a reduce
    int b = tid, p = 0;
    for (int t=0;t<D;++t){
      int m = trans[t*256 + gb0 + b];
      short li = 0;
      if (m) li = (short)stk_[b][p-2];
      mS[t][b] = (uint8_t)m; liA[t][b] = li;
      int np = p - 2*m; stk_[b][np] = (unsigned short)t; p = np + 1;
    }
  }
  __syncthreads();

  // --- prefill xs[0]: emb(labels[0]) + leaf (mask(0)==0 by construction) ---
  if (tid < 320){
    const int b = (tid >= 160) ? 1 : 0;
    const int r = tid - b*160;
    float v;
    if (r < 32)       v = emb[(size_t)labels[gb0 + b]*LD + sl*32 + r];
    else if (r < 96)  v = lshd[sl*64 + (r-32)];
    else              v = lshd[sl*64 + (r-96)];
    xs[0][b][r] = v;
  }
  __syncthreads();

  float ccprev = 0.f;   // own c[t-1][b][dl] (cell threads only)

  for (int t=0;t<D;++t){
    const int cur = t&1, nxt = cur^1;

    // ---- P1: pass A — partials for PARTNER's 320 cols, all 8 waves ----
    GEMM_PASS(wa, gpA, ;);
    __syncthreads();

    // ---- P2: reduce + send (self-tagged words), then pass B (own cols) ----
    const size_t xoS = ((((size_t)(unsigned)(t&3))*128 + g2)*2 + ps)*640;
    {
      const int w = tid;
      float a = gpA[0][w];
#pragma unroll
      for (int kk=1;kk<8;++kk) a += gpA[kk][w];
      gst64x(Xbuf + xoS + w, packw(a, (unsigned)(t+1)));
    }
    if (tid < 128){
      const int w = 512 + tid;
      float a = gpA[0][w];
#pragma unroll
      for (int kk=1;kk<8;++kk) a += gpA[kk][w];
      gst64x(Xbuf + xoS + w, packw(a, (unsigned)(t+1)));
    }

    const u64t* Xr = Xbuf + ((((size_t)(unsigned)(t&3))*128 + g2)*2 + sl)*640;
    const int bc = tid >> 6, dlc = tid & 63;   // cell coords (valid tid<128)
    u64t pw[5];
    GEMM_PASS(wb, gpB,
      if (tid < 128){
        _Pragma("unroll")
        for (int g=0;g<5;++g) pw[g] = gld64x(Xr + g*128 + dlc*2 + bc);
      }
    );
    __syncthreads();

    // ---- P3: cell (waves 0-1) || prefetch t+1 (waves 2-4) ----
    if (tid < 128){
      const int b = bc, dl = dlc, gd = sl*64 + dl;
      const int m = mS[t][b];
      // own-K partials + bias (overlaps outstanding poll loads)
      float s[5];
#pragma unroll
      for (int g=0;g<5;++g){
        const int w = g*128 + dl*2 + b;
        float a = bsl[g*64 + dl];
#pragma unroll
        for (int kk=0;kk<8;++kk) a += gpB[kk][w];
        s[g] = a;
      }
      // validate partner words; retry if stale (rare in steady state)
      const unsigned want = (unsigned)(t+1);
      int it = 0;
      while (((unsigned)(pw[0]>>32) != want) | ((unsigned)(pw[1]>>32) != want) |
             ((unsigned)(pw[2]>>32) != want) | ((unsigned)(pw[3]>>32) != want) |
             ((unsigned)(pw[4]>>32) != want)){
        __builtin_amdgcn_s_sleep(1);
#pragma unroll
        for (int g=0;g<5;++g) pw[g] = gld64x(Xr + g*128 + dl*2 + b);
        if (++it > (1<<20)) break;   // safety: hang -> wrong answer
      }
#pragma unroll
      for (int g=0;g<5;++g) s[g] += __uint_as_float((unsigned)(pw[g] & 0xffffffffu));

      const float cl_ = m ? clb[cur][b][dl] : lshd[gd];
      const float cr_ = m ? ccprev : lshd[gd];       // ri == t-1: own prev c
      const float cc = sigf(s[0])*tanh_(s[4]) + sigf(s[1])*cl_ + sigf(s[2])*cr_;
      const float hh = sigf(s[3])*tanh_(cc);
      ccprev = cc;

      hrec[((size_t)t*2 + b)*64 + dl] = hh;   // plain, intra-block only
      crec[((size_t)t*2 + b)*64 + dl] = cc;

      if (t == D-1){
        out[(size_t)(gb0+b)*HD + gd] = cc;
        out[(size_t)256*HD + (size_t)(gb0+b)*HD + gd] = hh;
      } else {
        xs[nxt][b][96+dl] = mS[t+1][b] ? hh : lshd[gd];  // own hr half for t+1
      }
      if (t+2 < D && mS[t+2][b] && liA[t+2][b] == t){
        xs[cur][b][32+dl] = hh;     // own hl half for t+2 (li==t case)
        clb[cur][b][dl]   = cc;
      }
    } else if (kg == 2){            // emb(t+1), own 32 label rows
      if (t+1 < D){
        const int b = lane>>5, i2 = lane&31;
        const int row = labels[(t+1)*256 + gb0 + b];
        xs[nxt][b][i2] = emb[(size_t)row*LD + sl*32 + i2];
      }
    } else if (kg == 3){            // hl own half for t+1
      if (t+1 < D){
        const int b = lane>>5, jj = lane&31;
        const int m1 = mS[t+1][b]; const int li = liA[t+1][b];
        if (m1){
          if (li <= t-2){
            const float2 hv = *(const float2*)(hrec + ((size_t)li*2 + b)*64 + jj*2);
            xs[nxt][b][32+jj*2]   = hv.x;
            xs[nxt][b][32+jj*2+1] = hv.y;
          }
          // li == t-1: cell@t-1 already wrote xs/clb from registers
        } else {
          xs[nxt][b][32+jj*2]   = lshd[sl*64 + jj*2];
          xs[nxt][b][32+jj*2+1] = lshd[sl*64 + jj*2+1];
        }
      }
    } else if (kg == 4){            // cl own half for t+1
      if (t+1 < D){
        const int b = lane>>5, jj = lane&31;
        const int m1 = mS[t+1][b]; const int li = liA[t+1][b];
        if (m1){
          if (li <= t-2){
            const float2 cv = *(const float2*)(crec + ((size_t)li*2 + b)*64 + jj*2);
            clb[nxt][b][jj*2]   = cv.x;
            clb[nxt][b][jj*2+1] = cv.y;
          }
        } else {
          clb[nxt][b][jj*2]   = lshd[sl*64 + jj*2];
          clb[nxt][b][jj*2+1] = lshd[sl*64 + jj*2+1];
        }
      }
    }
    __syncthreads();
  }
}

extern "C" void kernel_launch(void* const* d_in, const int* in_sizes, int n_in,
                              void* d_out, int out_size, void* d_ws, size_t ws_size,
                              hipStream_t stream) {
  (void)in_sizes; (void)n_in; (void)out_size; (void)ws_size;
  const int*   trans  = (const int*)d_in[0];
  const int*   labels = (const int*)d_in[1];
  const float* emb    = (const float*)d_in[2];
  const float* W      = (const float*)d_in[3];
  const float* bias   = (const float*)d_in[4];
  const float* leaf   = (const float*)d_in[5];
  float* out = (float*)d_out;

  // ws: [0, 5.25MB)  X ring: 4 x 128 x 2 x 640 self-tagged u64 partial words
  //     (tag = t+1, so zero-init AND 0xAA-poison are both != any live tag;
  //      slot reuse distance 4 steps; pair skew bounded <2 steps by the
  //      per-step partial dependency -> no overwrite hazard)
  //     [8MB,72MB)  hrec: own-half h records, intra-block plain cached
  //     [72MB,136MB) crec: own-half c records, intra-block plain cached
  uint8_t* ws = (uint8_t*)d_ws;
  u64t*  Xbuf = (u64t*)ws;
  float* hrec = (float*)(ws + ((size_t)8<<20));
  float* crec = (float*)(ws + ((size_t)72<<20));

  spinn_kernel<<<dim3(256), dim3(NTHR), 0, stream>>>(
      trans, labels, emb, W, bias, leaf, out, Xbuf, hrec, crec);
}

// Round 2
// 1934.241 us; speedup vs baseline: 8.7396x; 8.7396x over previous
//
#include <hip/hip_runtime.h>
#include <stdint.h>

// SPINN thin-stack TreeLSTM, MI355X, round 8: early-exchange 2-phase schedule.
// Structure = round 6 (verified AGPR-resident GEMM: 128 groups x 2 blocks,
// block owns 64 H-dims / 320 gate cols, W-slice 200 f32/thread in wr4/wr1),
// but: (1) P1 = ALL 8 waves GEMM full K=320 (was 4+4 over two phases);
// (2) partner h(t) is polled during P3(t) by wave 7 (partner publishes it
// mid-P3(t) in lockstep) and deposited into xs[nxt] BEFORE the step barrier,
// so P1 has no cross-block dependency at all; (3) h-records are SELF-TAGGED
// (f32,t+1) u64 words in an 8-deep ring -> no tag array, no vmcnt(0) drain
// in the cell, one fabric trip per poll instead of two.
// 2 barriers/step. Plain f32 rec/cown kept for old (li<=t-2) readers
// (>=2-step-old stores, flight-time safe — same assumption round 6 shipped).

#define D     512
#define HD    128
#define LD    64
#define NTHR  512
#define GPR   328   // gp row stride (floats): 256 quad cols + 64 u cols + pad

typedef unsigned long long u64t;

__device__ __forceinline__ float sigf(float x){ return 1.0f/(1.0f+__expf(-x)); }
__device__ __forceinline__ float tanh_(float x){ return 1.0f-2.0f/(__expf(2.0f*x)+1.0f); }
__device__ __forceinline__ u64t gld64(const float* p){
  return __hip_atomic_load((const u64t*)p, __ATOMIC_RELAXED, __HIP_MEMORY_SCOPE_AGENT);
}
__device__ __forceinline__ u64t gld64r(const u64t* p){
  return __hip_atomic_load(p, __ATOMIC_RELAXED, __HIP_MEMORY_SCOPE_AGENT);
}
__device__ __forceinline__ void gst32(float* p, float v){
  __hip_atomic_store(p, v, __ATOMIC_RELAXED, __HIP_MEMORY_SCOPE_AGENT);
}
__device__ __forceinline__ void gst64r(u64t* p, u64t v){
  __hip_atomic_store(p, v, __ATOMIC_RELAXED, __HIP_MEMORY_SCOPE_AGENT);
}
__device__ __forceinline__ u64t packw(float v, unsigned tg){
  return ((u64t)tg << 32) | (u64t)__float_as_uint(v);
}
__device__ __forceinline__ float loww(u64t w){
  return __uint_as_float((unsigned)(w & 0xffffffffu));
}

__global__ __launch_bounds__(NTHR,2) void spinn_kernel(
    const int* __restrict__ trans, const int* __restrict__ labels,
    const float* __restrict__ emb, const float* __restrict__ W,
    const float* __restrict__ bias, const float* __restrict__ leaf,
    float* __restrict__ out, u64t* __restrict__ ring,
    float* __restrict__ rec, float* __restrict__ cown)
{
  const int bid = blockIdx.x;
  const int g2 = bid>>1, sl = bid&1, ps = sl^1;
  const int gb0 = g2*2;
  const int tid = threadIdx.x;
  const int kg = tid>>6, lane = tid&63;
  const int cq = lane;

  __shared__ __align__(16) float xs[2][2][320];     // [buf][b][k]: 64 lab|128 hl|128 hr
  __shared__ __align__(16) float gpq[16][GPR];      // [(kg*2+b)][col]
  __shared__ float bsl[320];
  __shared__ float lshd[HD];
  __shared__ float clb[2][2][64];
  __shared__ uint8_t mS[D][2];
  __shared__ short liA[D][2];
  __shared__ unsigned short stk_[2][D];

  // --- W slice into registers: 40 K-rows x (4 quad cols + 1 u col) ---
  // (kept byte-identical to round 6 — this allocation is AGPR-resident)
  float4 wr4[40]; float wr1[40];
  {
    const int gq = (cq>>4)*128 + sl*64 + ((cq*4)&63);  // quad base (gates 0-3)
    const int gu = 512 + sl*64 + cq;                   // u-gate col
#pragma unroll
    for (int j=0;j<40;++j){
      int k = kg*40 + j;
      wr4[j] = *(const float4*)(W + (size_t)k*640 + gq);
      wr1[j] = W[(size_t)k*640 + gu];
    }
  }
  if (tid < 320){
    int c = tid;
    int gc = (c < 256) ? ((c>>6)*128 + sl*64 + (c&63)) : (512 + sl*64 + (c-256));
    bsl[c] = bias[gc];
  }
  if (tid < HD) lshd[tid] = leaf[tid];
  if (tid < 2){   // precompute (mask, li); ri == t-1 always on a reduce
    int b = tid, p = 0;
    for (int t=0;t<D;++t){
      int m = trans[t*256 + gb0 + b];
      short li = 0;
      if (m) li = (short)stk_[b][p-2];
      mS[t][b] = (uint8_t)m; liA[t][b] = li;
      int np = p - 2*m; stk_[b][np] = (unsigned short)t; p = np+1;
    }
  }
  __syncthreads();

  // --- prefill xs[0]: emb(labels[0]) + leaf (mask(0)==0 by construction) ---
  for (int idx = tid; idx < 640; idx += NTHR){
    int b = (idx >= 320) ? 1 : 0;
    int r = idx - b*320;
    if (r < 64){
      int row = labels[gb0 + b];
      xs[0][b][r] = emb[(size_t)row*LD + r];
    } else {
      xs[0][b][r] = lshd[(r-64)&127];
    }
  }
  __syncthreads();

  auto gemm = [&](int cur){
    float4 a0 = {0.f,0.f,0.f,0.f}, a1 = {0.f,0.f,0.f,0.f};
    float u0 = 0.f, u1 = 0.f;
#pragma unroll
    for (int j4=0;j4<10;++j4){
      int k = kg*40 + j4*4;
      float4 x0 = *(const float4*)&xs[cur][0][k];   // broadcast (all lanes same)
      float4 x1 = *(const float4*)&xs[cur][1][k];
      float xa0[4] = {x0.x,x0.y,x0.z,x0.w};
      float xa1[4] = {x1.x,x1.y,x1.z,x1.w};
#pragma unroll
      for (int jj=0;jj<4;++jj){
        float4 w = wr4[j4*4+jj];
        float wu = wr1[j4*4+jj];
        a0.x = __builtin_fmaf(w.x, xa0[jj], a0.x);
        a0.y = __builtin_fmaf(w.y, xa0[jj], a0.y);
        a0.z = __builtin_fmaf(w.z, xa0[jj], a0.z);
        a0.w = __builtin_fmaf(w.w, xa0[jj], a0.w);
        a1.x = __builtin_fmaf(w.x, xa1[jj], a1.x);
        a1.y = __builtin_fmaf(w.y, xa1[jj], a1.y);
        a1.z = __builtin_fmaf(w.z, xa1[jj], a1.z);
        a1.w = __builtin_fmaf(w.w, xa1[jj], a1.w);
        u0 = __builtin_fmaf(wu, xa0[jj], u0);
        u1 = __builtin_fmaf(wu, xa1[jj], u1);
      }
    }
    *(float4*)&gpq[kg*2+0][cq*4] = a0;
    *(float4*)&gpq[kg*2+1][cq*4] = a1;
    gpq[kg*2+0][256+cq] = u0;
    gpq[kg*2+1][256+cq] = u1;
  };

  float ccprev = 0.f;   // own c[t-1][b][dl] (cell threads only)

  for (int t=0;t<D;++t){
    const int cur = t&1, nxt = cur^1;

    // ---- P1: ALL 8 waves GEMM the full K=320 (xs[cur] complete) ----
    gemm(cur);
    __syncthreads();

    // ---- P2: cell (waves 0-1) || prefetch t+1 (2,3,6) || exchange (7) ----
    if (tid < 128){
      const int b = tid>>6, dl = tid&63, gd = sl*64+dl;
      const int m = mS[t][b];
      float s[5];
#pragma unroll
      for (int g=0; g<5; ++g){
        int c = (g<4) ? (g*64+dl) : (256+dl);
        float a = 0.f;
#pragma unroll
        for (int kk=0; kk<8; ++kk) a += gpq[kk*2+b][c];
        s[g] = a + bsl[c];
      }
      float cl_ = m ? clb[cur][b][dl] : lshd[gd];
      float cr_ = m ? ccprev : lshd[gd];            // ri == t-1: own prev c
      float cc = sigf(s[0])*tanh_(s[4]) + sigf(s[1])*cl_ + sigf(s[2])*cr_;
      float hh = sigf(s[3])*tanh_(cc);
      ccprev = cc;
      // publish self-tagged h FIRST (partner's critical path); no drain needed
      gst64r(ring + (((size_t)(t&7)*128 + g2)*2 + sl)*128 + tid,
             packw(hh, (unsigned)(t+1)));
      size_t ro = (((size_t)t*128 + g2)*2 + sl)*128 + b*64 + dl;
      gst32(rec + ro, hh);
      gst32(cown + ro, cc);
      if (t == D-1){
        out[(size_t)(gb0+b)*HD + gd] = cc;
        out[(size_t)256*HD + (size_t)(gb0+b)*HD + gd] = hh;
      } else {
        xs[nxt][b][192+gd] = mS[t+1][b] ? hh : lshd[gd];   // own hr for t+1
      }
      if (t+2 < D && mS[t+2][b] && liA[t+2][b] == t){
        xs[cur][b][64+gd]  = hh;    // own hl for t+2 (li==t case)
        clb[cur][b][dl]    = cc;    // own cl for t+2
      }
    } else if (kg == 2){            // emb(t+1)
      if (t+1 < D){
        int b = lane>>5, jj = lane&31;
        int row = labels[(t+1)*256 + gb0 + b];
        float2 ev = *(const float2*)(emb + (size_t)row*LD + jj*2);
        xs[nxt][b][jj*2]   = ev.x;
        xs[nxt][b][jj*2+1] = ev.y;
      }
    } else if (kg == 3){            // own-slice hl/cl for t+1
      if (t+1 < D){
        int b = lane>>5, jj = lane&31;
        int m1 = mS[t+1][b]; int li = liA[t+1][b];
        if (m1){
          if (li <= t-2){
            size_t ro = (((size_t)li*128+g2)*2 + sl)*128 + b*64 + jj*2;
            union{u64t u; float f[2];} h_, c_;
            h_.u = gld64(rec + ro);
            c_.u = gld64(cown + ro);
            xs[nxt][b][64+sl*64+jj*2]   = h_.f[0];
            xs[nxt][b][64+sl*64+jj*2+1] = h_.f[1];
            clb[nxt][b][jj*2]   = c_.f[0];
            clb[nxt][b][jj*2+1] = c_.f[1];
          }
          // li == t-1: cell@t-1 already wrote xs/clb from registers
        } else {
          xs[nxt][b][64+sl*64+jj*2]   = lshd[sl*64+jj*2];
          xs[nxt][b][64+sl*64+jj*2+1] = lshd[sl*64+jj*2+1];
          clb[nxt][b][jj*2]   = lshd[sl*64+jj*2];
          clb[nxt][b][jj*2+1] = lshd[sl*64+jj*2+1];
        }
      }
    } else if (kg == 6){            // partner-slice hl for t+1
      if (t+1 < D){
        int b = lane>>5, jj = lane&31;
        int m1 = mS[t+1][b]; int li = liA[t+1][b];
        if (m1){
          if (li <= t-2){
            size_t ro = (((size_t)li*128+g2)*2 + ps)*128 + b*64 + jj*2;
            union{u64t u; float f[2];} h_;
            h_.u = gld64(rec + ro);
            xs[nxt][b][64+ps*64+jj*2]   = h_.f[0];
            xs[nxt][b][64+ps*64+jj*2+1] = h_.f[1];
          } else {                  // li == t-1: ring slot confirmed at P2(t-1)
            const u64t* rp = ring + (((size_t)((t-1)&7)*128 + g2)*2 + ps)*128
                             + b*64 + jj*2;
            xs[nxt][b][64+ps*64+jj*2]   = loww(gld64r(rp));
            xs[nxt][b][64+ps*64+jj*2+1] = loww(gld64r(rp+1));
          }
        } else {
          xs[nxt][b][64+ps*64+jj*2]   = lshd[ps*64+jj*2];
          xs[nxt][b][64+ps*64+jj*2+1] = lshd[ps*64+jj*2+1];
        }
      }
    } else if (kg == 7){            // poll partner h(t); deposit hr for t+1
      if (t+1 < D){
        const u64t* rp = ring + (((size_t)(t&7)*128 + g2)*2 + ps)*128 + lane*2;
        const unsigned want = (unsigned)(t+1);
        u64t w0 = 0, w1 = 0; int it = 0;
        for (;;){
          w0 = gld64r(rp); w1 = gld64r(rp+1);
          int ok = ((unsigned)(w0>>32) == want) & ((unsigned)(w1>>32) == want);
          if (__all(ok)) break;
          __builtin_amdgcn_s_sleep(1);
          if (++it > (1<<20)) break;   // safety: hang -> wrong answer
        }
        int b = lane>>5, jj = lane&31;
        if (mS[t+1][b]){
          xs[nxt][b][192+ps*64+jj*2]   = loww(w0);
          xs[nxt][b][192+ps*64+jj*2+1] = loww(w1);
        } else {
          xs[nxt][b][192+ps*64+jj*2]   = lshd[ps*64+jj*2];
          xs[nxt][b][192+ps*64+jj*2+1] = lshd[ps*64+jj*2+1];
        }
      }
    }
    __syncthreads();
  }
}

extern "C" void kernel_launch(void* const* d_in, const int* in_sizes, int n_in,
                              void* d_out, int out_size, void* d_ws, size_t ws_size,
                              hipStream_t stream) {
  (void)in_sizes; (void)n_in; (void)out_size; (void)ws_size;
  const int*   trans  = (const int*)d_in[0];
  const int*   labels = (const int*)d_in[1];
  const float* emb    = (const float*)d_in[2];
  const float* W      = (const float*)d_in[3];
  const float* bias   = (const float*)d_in[4];
  const float* leaf   = (const float*)d_in[5];
  float* out = (float*)d_out;

  // ws: [0, 2MB)   ring: 8-deep self-tagged h records, u64 per (slot,g2,sl,b,dl)
  //               (tag = t+1: 0xAA poison AND zero-init != any live tag;
  //                slot reuse distance 8 steps, pair skew <=1 step -> safe)
  //     [8MB,72MB)  rec:  plain h records (li<=t-2 readers, >=2 steps old)
  //     [72MB,136MB) cown: plain c records (own-block readers only)
  uint8_t* ws = (uint8_t*)d_ws;
  u64t*  ring = (u64t*)ws;
  float* rec  = (float*)(ws + ((size_t)8<<20));
  float* cown = (float*)(ws + ((size_t)72<<20));

  spinn_kernel<<<dim3(256), dim3(NTHR), 0, stream>>>(
      trans, labels, emb, W, bias, leaf, out, ring, rec, cown);
}